// Round 10
// baseline (278.631 us; speedup 1.0000x reference)
//
#include <hip/hip_runtime.h>
#include <math.h>

#define BB 4
#define LL 4096
#define DD 256
#define NROWS (BB*LL)      // 16384
#define CHUNK 32
#define NC (LL/CHUNK)      // 128
#define NB 8192            // counting-sort bins
#define PBLK 512           // k_post grid (2 blocks/CU -> co-resident)

typedef __bf16 bf16x8 __attribute__((ext_vector_type(8)));
typedef float floatx4 __attribute__((ext_vector_type(4)));

// ---------------- K1: u = {Wq^T w, Wk^T w} + split Wv -> Wh+Wl (no atomics) ----------------
// 16 blocks x 256 thr; block g owns output d-range [16g, 16g+16).
__global__ void __launch_bounds__(256) k_prep(const float* __restrict__ Wq,
        const float* __restrict__ Wk, const float* __restrict__ Wv,
        const float* __restrict__ w, float* __restrict__ u,
        __bf16* __restrict__ Wh, __bf16* __restrict__ Wl) {
    __shared__ float pq[256*17];   // pad 17: reduce reads stride 17 -> all banks
    __shared__ float pk[256*17];
    __shared__ float rq[16*17], rk[16*17];
    int e = threadIdx.x;
    int d0 = blockIdx.x * 16;
    float we = w[e];
    #pragma unroll
    for (int j4 = 0; j4 < 4; ++j4) {
        float4 q4 = *(const float4*)(Wq + (size_t)e*DD + d0 + j4*4);
        float4 k4 = *(const float4*)(Wk + (size_t)e*DD + d0 + j4*4);
        float4 v4 = *(const float4*)(Wv + (size_t)e*DD + d0 + j4*4);
        float qa[4] = {q4.x, q4.y, q4.z, q4.w};
        float ka[4] = {k4.x, k4.y, k4.z, k4.w};
        float va[4] = {v4.x, v4.y, v4.z, v4.w};
        #pragma unroll
        for (int j = 0; j < 4; ++j) {
            pq[e*17 + j4*4 + j] = qa[j] * we;
            pk[e*17 + j4*4 + j] = ka[j] * we;
            __bf16 h = (__bf16)va[j];
            Wh[(size_t)e*DD + d0 + j4*4 + j] = h;
            Wl[(size_t)e*DD + d0 + j4*4 + j] = (__bf16)(va[j] - (float)h);
        }
    }
    __syncthreads();
    int d = e & 15, g = e >> 4;
    float sq = 0.f, sk = 0.f;
    #pragma unroll
    for (int i = 0; i < 16; ++i) {
        sq += pq[(g*16 + i)*17 + d];
        sk += pk[(g*16 + i)*17 + d];
    }
    rq[g*17 + d] = sq;
    rk[g*17 + d] = sk;
    __syncthreads();
    if (e < 16) {
        float s1 = 0.f, s2 = 0.f;
        #pragma unroll
        for (int gg = 0; gg < 16; ++gg) { s1 += rq[gg*17 + e]; s2 += rk[gg*17 + e]; }
        u[d0 + e] = s1;
        u[DD + d0 + e] = s2;
    }
}

// ---------------- K2: V = x @ Wv^T, split-bf16 MFMA, NO LDS / NO BARRIERS ----------------
// Each lane loads its A fragment (8 fp32 of one x row) direct from global and
// splits in-register; B fragments direct from L2 (Wh/Wl = 256 KB, hot).
// Zero __syncthreads in the K-loop -> no barrier-drain stall (m97-class fix).
// mfma_f32_16x16x32_bf16, m89 layouts: A[m=l16][k=quad*8+j], B[n=l16][k=quad*8+j],
// C/D row=quad*4+i, col=l16. Proj (a,c) fused on wave 0's A loads, shfl reduce.
__global__ void __launch_bounds__(256) k_gemm(const float* __restrict__ x,
        const __bf16* __restrict__ Wh, const __bf16* __restrict__ Wl,
        const float* __restrict__ u, const float* __restrict__ bmlp,
        float* __restrict__ V, float* __restrict__ a, float* __restrict__ c) {
    const int tid = threadIdx.x;
    const int wave = tid >> 6, lane = tid & 63;
    const int quad = lane >> 4, l16 = lane & 15;
    const int rowBase = blockIdx.x * 32;

    floatx4 acc[2][4];
    #pragma unroll
    for (int rt = 0; rt < 2; ++rt)
        #pragma unroll
        for (int ct = 0; ct < 4; ++ct)
            acc[rt][ct] = (floatx4){0.f, 0.f, 0.f, 0.f};
    float aq0 = 0.f, aq1 = 0.f, ak0 = 0.f, ak1 = 0.f;

    #pragma unroll 1   // prevent load-hoist register blowup (r4 spill lesson)
    for (int k0 = 0; k0 < DD; k0 += 32) {
        const int kq = k0 + quad*8;
        bf16x8 ah[2], al[2];
        float4 x0[2], x1[2];
        #pragma unroll
        for (int rt = 0; rt < 2; ++rt) {
            const float* xp = x + (size_t)(rowBase + rt*16 + l16)*DD + kq;
            x0[rt] = *(const float4*)xp;
            x1[rt] = *(const float4*)(xp + 4);
            float xs[8] = {x0[rt].x, x0[rt].y, x0[rt].z, x0[rt].w,
                           x1[rt].x, x1[rt].y, x1[rt].z, x1[rt].w};
            #pragma unroll
            for (int j = 0; j < 8; ++j) {
                __bf16 h = (__bf16)xs[j];
                ah[rt][j] = h;
                al[rt][j] = (__bf16)(xs[j] - (float)h);
            }
        }
        if (wave == 0) {
            float4 uq0 = *(const float4*)(u + kq);
            float4 uq1 = *(const float4*)(u + kq + 4);
            float4 uk0 = *(const float4*)(u + DD + kq);
            float4 uk1 = *(const float4*)(u + DD + kq + 4);
            aq0 += x0[0].x*uq0.x + x0[0].y*uq0.y + x0[0].z*uq0.z + x0[0].w*uq0.w
                 + x1[0].x*uq1.x + x1[0].y*uq1.y + x1[0].z*uq1.z + x1[0].w*uq1.w;
            aq1 += x0[1].x*uq0.x + x0[1].y*uq0.y + x0[1].z*uq0.z + x0[1].w*uq0.w
                 + x1[1].x*uq1.x + x1[1].y*uq1.y + x1[1].z*uq1.z + x1[1].w*uq1.w;
            ak0 += x0[0].x*uk0.x + x0[0].y*uk0.y + x0[0].z*uk0.z + x0[0].w*uk0.w
                 + x1[0].x*uk1.x + x1[0].y*uk1.y + x1[0].z*uk1.z + x1[0].w*uk1.w;
            ak1 += x0[1].x*uk0.x + x0[1].y*uk0.y + x0[1].z*uk0.z + x0[1].w*uk0.w
                 + x1[1].x*uk1.x + x1[1].y*uk1.y + x1[1].z*uk1.z + x1[1].w*uk1.w;
        }
        #pragma unroll
        for (int ct = 0; ct < 4; ++ct) {
            int n = wave*64 + ct*16 + l16;
            bf16x8 bh = *(const bf16x8*)(Wh + (size_t)n*DD + kq);
            bf16x8 bl = *(const bf16x8*)(Wl + (size_t)n*DD + kq);
            #pragma unroll
            for (int rt = 0; rt < 2; ++rt) {
                acc[rt][ct] = __builtin_amdgcn_mfma_f32_16x16x32_bf16(ah[rt], bh, acc[rt][ct], 0, 0, 0);
                acc[rt][ct] = __builtin_amdgcn_mfma_f32_16x16x32_bf16(ah[rt], bl, acc[rt][ct], 0, 0, 0);
                acc[rt][ct] = __builtin_amdgcn_mfma_f32_16x16x32_bf16(al[rt], bh, acc[rt][ct], 0, 0, 0);
            }
        }
    }
    #pragma unroll
    for (int rt = 0; rt < 2; ++rt)
        #pragma unroll
        for (int ct = 0; ct < 4; ++ct)
            #pragma unroll
            for (int i = 0; i < 4; ++i)
                V[(size_t)(rowBase + rt*16 + quad*4 + i)*DD + wave*64 + ct*16 + l16]
                    = acc[rt][ct][i];
    if (wave == 0) {
        aq0 += __shfl_xor(aq0, 16); aq0 += __shfl_xor(aq0, 32);
        aq1 += __shfl_xor(aq1, 16); aq1 += __shfl_xor(aq1, 32);
        ak0 += __shfl_xor(ak0, 16); ak0 += __shfl_xor(ak0, 32);
        ak1 += __shfl_xor(ak1, 16); ak1 += __shfl_xor(ak1, 32);
        if (lane < 16) {
            float bias = bmlp[0];
            a[rowBase + lane]      = aq0 + bias;
            a[rowBase + 16 + lane] = aq1 + bias;
            c[rowBase + lane]      = ak0;
            c[rowBase + 16 + lane] = ak1;
        }
    }
}

// ---------------- K3: counting sort by value-bin + SE prefix ----------------
__global__ void __launch_bounds__(1024) k_sortish(const float* __restrict__ c,
        int* __restrict__ binstart_g, int* __restrict__ perm,
        float* __restrict__ c_sorted, float* __restrict__ e_sorted,
        float* __restrict__ SE, float* __restrict__ hdr) {
    __shared__ float cl[LL];
    __shared__ int   hist[NB];
    __shared__ float esl[LL];
    __shared__ float scrf[64];
    int b = blockIdx.x, tid = threadIdx.x;
    int wave = tid >> 6, lane = tid & 63;
    int* scri = (int*)scrf;

    float4 cv = ((const float4*)(c + (size_t)b*LL))[tid];
    ((float4*)cl)[tid] = cv;
    float cw[4] = {cv.x, cv.y, cv.z, cv.w};
    float mn = fminf(fminf(cw[0],cw[1]), fminf(cw[2],cw[3]));
    float mx = fmaxf(fmaxf(cw[0],cw[1]), fmaxf(cw[2],cw[3]));
    #pragma unroll
    for (int off = 32; off > 0; off >>= 1) {
        mn = fminf(mn, __shfl_down(mn, off));
        mx = fmaxf(mx, __shfl_down(mx, off));
    }
    if (lane == 0) { scrf[wave] = mn; scrf[32 + wave] = mx; }
    __syncthreads();
    if (wave == 0) {
        float m = (lane < 16) ? scrf[lane]      :  3.4e38f;
        float M = (lane < 16) ? scrf[32 + lane] : -3.4e38f;
        #pragma unroll
        for (int off = 32; off > 0; off >>= 1) {
            m = fminf(m, __shfl_down(m, off));
            M = fmaxf(M, __shfl_down(M, off));
        }
        if (lane == 0) { scrf[0] = m; scrf[1] = M; }
    }
    __syncthreads();
    float cmin = scrf[0], cmax = scrf[1];
    float scale = (float)NB / fmaxf(cmax - cmin, 1e-20f);
    __syncthreads();

    ((int4*)hist)[tid] = make_int4(0,0,0,0);
    ((int4*)hist)[tid + 1024] = make_int4(0,0,0,0);
    __syncthreads();

    int bins[4];
    #pragma unroll
    for (int u = 0; u < 4; ++u) {
        int bi = (int)((cw[u] - cmin) * scale);
        bi = bi < 0 ? 0 : (bi > NB-1 ? NB-1 : bi);
        bins[u] = bi;
        atomicAdd(&hist[bi], 1);
    }
    __syncthreads();

    int loc[8]; int base = 0;
    #pragma unroll
    for (int j = 0; j < 8; ++j) { loc[j] = base; base += hist[tid*8 + j]; }
    int incl = base;
    #pragma unroll
    for (int off = 1; off < 64; off <<= 1) {
        int t = __shfl_up(incl, off);
        if (lane >= off) incl += t;
    }
    if (lane == 63) scri[wave] = incl;
    __syncthreads();
    if (wave == 0) {
        int v = (lane < 16) ? scri[lane] : 0;
        int s = v;
        #pragma unroll
        for (int off = 1; off < 16; off <<= 1) {
            int t = __shfl_up(s, off);
            if (lane >= off) s += t;
        }
        if (lane < 16) scri[lane] = s - v;
    }
    __syncthreads();
    int thread_excl = (incl - base) + scri[wave];
    __syncthreads();
    #pragma unroll
    for (int j = 0; j < 8; ++j) {
        int bs = thread_excl + loc[j];
        binstart_g[(size_t)b*(NB+2) + tid*8 + j] = bs;
        hist[tid*8 + j] = bs;
    }
    if (tid == 0) {
        binstart_g[(size_t)b*(NB+2) + NB]     = LL;
        binstart_g[(size_t)b*(NB+2) + NB + 1] = LL;
        hdr[b*2 + 0] = cmin;
        hdr[b*2 + 1] = scale;
    }
    __syncthreads();

    #pragma unroll
    for (int u = 0; u < 4; ++u) {
        int i = tid*4 + u;
        int r = atomicAdd(&hist[bins[u]], 1);
        float e = expf(cmin - cw[u]);
        perm[(size_t)b*LL + r] = i;
        c_sorted[(size_t)b*LL + r] = cw[u];
        e_sorted[(size_t)b*LL + r] = e;
        esl[r] = e;
    }
    __syncthreads();

    float le[4]; float s0 = 0.f;
    #pragma unroll
    for (int u = 0; u < 4; ++u) { le[u] = s0; s0 += esl[tid*4 + u]; }
    float fincl = s0;
    #pragma unroll
    for (int off = 1; off < 64; off <<= 1) {
        float t = __shfl_up(fincl, off);
        if (lane >= off) fincl += t;
    }
    if (lane == 63) scrf[wave] = fincl;
    __syncthreads();
    if (wave == 0) {
        float v = (lane < 16) ? scrf[lane] : 0.f;
        float s = v;
        #pragma unroll
        for (int off = 1; off < 16; off <<= 1) {
            float t = __shfl_up(s, off);
            if (lane >= off) s += t;
        }
        if (lane < 16) scrf[lane] = s - v;
    }
    __syncthreads();
    float texcl = (fincl - s0) + scrf[wave];
    #pragma unroll
    for (int u = 0; u < 4; ++u)
        SE[(size_t)b*(LL+1) + tid*4 + u] = texcl + le[u];
    if (tid == 1023) SE[(size_t)b*(LL+1) + LL] = texcl + s0;
}

// ---------------- software grid barrier (one-shot counters, device scope) ----------------
__device__ __forceinline__ void grid_barrier(int* cnt, int expected) {
    __syncthreads();
    if (threadIdx.x == 0) {
        __threadfence();                       // release all prior writes, device scope
        atomicAdd(cnt, 1);
        while (atomicAdd(cnt, 0) < expected) { __builtin_amdgcn_s_sleep(4); }
        __threadfence();                       // acquire
    }
    __syncthreads();
}

// ---------------- K4: fused scan -> base -> out (512 blocks x 256 thr, co-resident) ----------------
__global__ void __launch_bounds__(256) k_post(
        const float* __restrict__ V, const int* __restrict__ perm,
        const float* __restrict__ e_sorted,
        float* __restrict__ Pl, float* __restrict__ Pel,
        float* __restrict__ Tp, float* __restrict__ Te,
        float* __restrict__ baseP, float* __restrict__ basePe,
        const float* __restrict__ a, const float* __restrict__ hdr,
        const int* __restrict__ binstart, const float* __restrict__ c_sorted,
        const float* __restrict__ SE, float* __restrict__ out,
        int* __restrict__ bar) {
    __shared__ int pj[CHUNK];
    __shared__ float pe[CHUNK];
    const int bid = blockIdx.x, tid = threadIdx.x;

    // ---- phase 1: chunked exclusive prefix (block = (q = bid&127, b = bid>>7)) ----
    {
        int q = bid & (NC-1), b = bid >> 7;
        int d = tid;
        if (d < CHUNK) {
            pj[d] = perm[(size_t)b*LL + q*CHUNK + d];
            pe[d] = e_sorted[(size_t)b*LL + q*CHUNK + d];
        }
        __syncthreads();
        float vr[CHUNK];
        #pragma unroll
        for (int r = 0; r < CHUNK; ++r)
            vr[r] = V[((size_t)b*LL + pj[r]) * DD + d];
        float acc = 0.f, acce = 0.f;
        size_t kb = (size_t)b*LL + (size_t)q*CHUNK;
        #pragma unroll
        for (int r = 0; r < CHUNK; ++r) {
            size_t o = (kb + r) * DD + d;
            Pl[o]  = acc;
            Pel[o] = acce;
            acc += vr[r];
            acce = fmaf(pe[r], vr[r], acce);
        }
        size_t to = ((size_t)b*NC + q) * DD + d;
        Tp[to] = acc;
        Te[to] = acce;
    }
    grid_barrier(&bar[0], PBLK);

    // ---- phase 2: chunk bases (tasks (q in [0,NC], b); 516 tasks over 512 blocks) ----
    for (int t = bid; t < (NC+1)*BB; t += PBLK) {
        int q = t >> 2, b = t & 3;
        float acc = 0.f, acce = 0.f;
        for (int i = 0; i < q; ++i) {
            size_t ti = ((size_t)b*NC + i) * DD + tid;
            acc += Tp[ti]; acce += Te[ti];
        }
        size_t o = ((size_t)b*(NC+1) + q) * DD + tid;
        baseP[o] = acc; basePe[o] = acce;
    }
    grid_barrier(&bar[1], PBLK);

    // ---- phase 3: per-row output (8 row-groups of 4 per block) ----
    for (int t = bid; t < NROWS/4; t += PBLK) {
        int row = t*4 + (tid >> 6);
        int lane = tid & 63;
        int b = row >> 12;
        float ai = a[row];
        float cmin = hdr[b*2 + 0], scale = hdr[b*2 + 1];
        float tt = (ai - cmin) * scale;
        int ib = tt < 0.f ? 0 : (tt >= (float)NB ? NB : (int)tt);
        int k    = binstart[(size_t)b*(NB+2) + ib];
        int kend = binstart[(size_t)b*(NB+2) + ib + 1];
        float alpha = expf(cmin - ai);
        float Z = fmaf(alpha, (float)(LL - k), SE[(size_t)b*(LL+1) + k]);
        size_t db = (size_t)lane * 4;
        size_t totoff = ((size_t)b * (NC+1) + NC) * DD + db;
        float4 ptot = *(const float4*)(baseP + totoff);
        float4 pk, pek;
        if (k < LL) {
            int q = k >> 5;
            size_t po = ((size_t)b * LL + k) * DD + db;
            size_t bo = ((size_t)b * (NC+1) + q) * DD + db;
            float4 pl = *(const float4*)(Pl    + po);
            float4 bp = *(const float4*)(baseP + bo);
            float4 pe4 = *(const float4*)(Pel    + po);
            float4 be = *(const float4*)(basePe + bo);
            pk.x = pl.x + bp.x; pk.y = pl.y + bp.y; pk.z = pl.z + bp.z; pk.w = pl.w + bp.w;
            pek.x = pe4.x + be.x; pek.y = pe4.y + be.y; pek.z = pe4.z + be.z; pek.w = pe4.w + be.w;
        } else {
            pk = ptot;
            pek = *(const float4*)(basePe + totoff);
        }
        float4 num;
        num.x = fmaf(alpha, ptot.x - pk.x, pek.x);
        num.y = fmaf(alpha, ptot.y - pk.y, pek.y);
        num.z = fmaf(alpha, ptot.z - pk.z, pek.z);
        num.w = fmaf(alpha, ptot.w - pk.w, pek.w);
        for (int r = k; r < kend; ++r) {
            float cr = c_sorted[(size_t)b*LL + r];
            if (cr < ai) {
                float w = e_sorted[(size_t)b*LL + r] - alpha;
                int j = perm[(size_t)b*LL + r];
                float4 v = *(const float4*)(V + ((size_t)b*LL + j) * DD + db);
                num.x = fmaf(w, v.x, num.x);
                num.y = fmaf(w, v.y, num.y);
                num.z = fmaf(w, v.z, num.z);
                num.w = fmaf(w, v.w, num.w);
                Z += w;
            }
        }
        float invZ = 1.f / Z;
        float4 o;
        o.x = num.x * invZ; o.y = num.y * invZ; o.z = num.z * invZ; o.w = num.w * invZ;
        *(float4*)(out + (size_t)row * DD + db) = o;
    }
}

extern "C" void kernel_launch(void* const* d_in, const int* in_sizes, int n_in,
                              void* d_out, int out_size, void* d_ws, size_t ws_size,
                              hipStream_t stream) {
    const float* x  = (const float*)d_in[0];
    const float* Wq = (const float*)d_in[1];
    const float* Wk = (const float*)d_in[2];
    const float* Wv = (const float*)d_in[3];
    const float* wm = (const float*)d_in[4];
    const float* bm = (const float*)d_in[5];
    float* out = (float*)d_out;
    float* ws = (float*)d_ws;

    size_t off = 0;
    auto alloc = [&](size_t n) {      // n in floats
        float* p = ws + off;
        off += (n + 255) & ~(size_t)255;
        return p;
    };
    float* u        = alloc(2*DD);
    float* a        = alloc(NROWS);
    float* c        = alloc(NROWS);
    float* c_sorted = alloc(NROWS);
    float* e_sorted = alloc(NROWS);
    float* SE       = alloc((size_t)BB*(LL+1));
    int*   perm     = (int*)alloc(NROWS);
    int*   binstart = (int*)alloc((size_t)BB*(NB+2));
    float* hdr      = alloc(2*BB);
    float* V        = alloc((size_t)NROWS*DD);
    float* Pl       = alloc((size_t)NROWS*DD);
    float* Pel      = alloc((size_t)NROWS*DD);
    float* Tp       = alloc((size_t)BB*NC*DD);
    float* Te       = alloc((size_t)BB*NC*DD);
    float* baseP    = alloc((size_t)BB*(NC+1)*DD);
    float* basePe   = alloc((size_t)BB*(NC+1)*DD);
    __bf16* Wh      = (__bf16*)alloc((size_t)DD*DD/2);
    __bf16* Wl      = (__bf16*)alloc((size_t)DD*DD/2);
    int*   bar      = (int*)alloc(64);

    hipMemsetAsync(bar, 0, 2*sizeof(int), stream);
    hipLaunchKernelGGL(k_prep, dim3(16), dim3(256), 0, stream, Wq, Wk, Wv, wm, u, Wh, Wl);
    hipLaunchKernelGGL(k_gemm, dim3(NROWS/32), dim3(256), 0, stream,
                       x, Wh, Wl, u, bm, V, a, c);
    hipLaunchKernelGGL(k_sortish, dim3(BB), dim3(1024), 0, stream,
                       c, binstart, perm, c_sorted, e_sorted, SE, hdr);
    hipLaunchKernelGGL(k_post, dim3(PBLK), dim3(256), 0, stream,
                       V, perm, e_sorted, Pl, Pel, Tp, Te, baseP, basePe,
                       a, hdr, binstart, c_sorted, SE, out, bar);
}

// Round 11
// 144.723 us; speedup vs baseline: 1.9253x; 1.9253x over previous
//
#include <hip/hip_runtime.h>
#include <math.h>

#define BB 4
#define LL 4096
#define DD 256
#define NROWS (BB*LL)      // 16384
#define CHUNK 32
#define NC (LL/CHUNK)      // 128
#define NB 8192            // counting-sort bins

typedef __bf16 bf16x8 __attribute__((ext_vector_type(8)));
typedef float floatx4 __attribute__((ext_vector_type(4)));

// ---------------- K1: u = {Wq^T w, Wk^T w} + split Wv -> Wh+Wl (no atomics) ----------------
__global__ void __launch_bounds__(256) k_prep(const float* __restrict__ Wq,
        const float* __restrict__ Wk, const float* __restrict__ Wv,
        const float* __restrict__ w, float* __restrict__ u,
        __bf16* __restrict__ Wh, __bf16* __restrict__ Wl) {
    __shared__ float pq[256*17];
    __shared__ float pk[256*17];
    __shared__ float rq[16*17], rk[16*17];
    int e = threadIdx.x;
    int d0 = blockIdx.x * 16;
    float we = w[e];
    #pragma unroll
    for (int j4 = 0; j4 < 4; ++j4) {
        float4 q4 = *(const float4*)(Wq + (size_t)e*DD + d0 + j4*4);
        float4 k4 = *(const float4*)(Wk + (size_t)e*DD + d0 + j4*4);
        float4 v4 = *(const float4*)(Wv + (size_t)e*DD + d0 + j4*4);
        float qa[4] = {q4.x, q4.y, q4.z, q4.w};
        float ka[4] = {k4.x, k4.y, k4.z, k4.w};
        float va[4] = {v4.x, v4.y, v4.z, v4.w};
        #pragma unroll
        for (int j = 0; j < 4; ++j) {
            pq[e*17 + j4*4 + j] = qa[j] * we;
            pk[e*17 + j4*4 + j] = ka[j] * we;
            __bf16 h = (__bf16)va[j];
            Wh[(size_t)e*DD + d0 + j4*4 + j] = h;
            Wl[(size_t)e*DD + d0 + j4*4 + j] = (__bf16)(va[j] - (float)h);
        }
    }
    __syncthreads();
    int d = e & 15, g = e >> 4;
    float sq = 0.f, sk = 0.f;
    #pragma unroll
    for (int i = 0; i < 16; ++i) {
        sq += pq[(g*16 + i)*17 + d];
        sk += pk[(g*16 + i)*17 + d];
    }
    rq[g*17 + d] = sq;
    rk[g*17 + d] = sk;
    __syncthreads();
    if (e < 16) {
        float s1 = 0.f, s2 = 0.f;
        #pragma unroll
        for (int gg = 0; gg < 16; ++gg) { s1 += rq[gg*17 + e]; s2 += rk[gg*17 + e]; }
        u[d0 + e] = s1;
        u[DD + d0 + e] = s2;
    }
}

// ---------------- K2: V = x @ Wv^T, split-bf16 MFMA, NO LDS / NO BARRIERS ----------------
// (r10 version, kept: zero __syncthreads in K-loop; A fragments direct from
// global with in-register split; B from L2; proj fused on wave 0.)
__global__ void __launch_bounds__(256) k_gemm(const float* __restrict__ x,
        const __bf16* __restrict__ Wh, const __bf16* __restrict__ Wl,
        const float* __restrict__ u, const float* __restrict__ bmlp,
        float* __restrict__ V, float* __restrict__ a, float* __restrict__ c) {
    const int tid = threadIdx.x;
    const int wave = tid >> 6, lane = tid & 63;
    const int quad = lane >> 4, l16 = lane & 15;
    const int rowBase = blockIdx.x * 32;

    floatx4 acc[2][4];
    #pragma unroll
    for (int rt = 0; rt < 2; ++rt)
        #pragma unroll
        for (int ct = 0; ct < 4; ++ct)
            acc[rt][ct] = (floatx4){0.f, 0.f, 0.f, 0.f};
    float aq0 = 0.f, aq1 = 0.f, ak0 = 0.f, ak1 = 0.f;

    #pragma unroll 1   // prevent load-hoist register blowup (r4 spill lesson)
    for (int k0 = 0; k0 < DD; k0 += 32) {
        const int kq = k0 + quad*8;
        bf16x8 ah[2], al[2];
        float4 x0[2], x1[2];
        #pragma unroll
        for (int rt = 0; rt < 2; ++rt) {
            const float* xp = x + (size_t)(rowBase + rt*16 + l16)*DD + kq;
            x0[rt] = *(const float4*)xp;
            x1[rt] = *(const float4*)(xp + 4);
            float xs[8] = {x0[rt].x, x0[rt].y, x0[rt].z, x0[rt].w,
                           x1[rt].x, x1[rt].y, x1[rt].z, x1[rt].w};
            #pragma unroll
            for (int j = 0; j < 8; ++j) {
                __bf16 h = (__bf16)xs[j];
                ah[rt][j] = h;
                al[rt][j] = (__bf16)(xs[j] - (float)h);
            }
        }
        if (wave == 0) {
            float4 uq0 = *(const float4*)(u + kq);
            float4 uq1 = *(const float4*)(u + kq + 4);
            float4 uk0 = *(const float4*)(u + DD + kq);
            float4 uk1 = *(const float4*)(u + DD + kq + 4);
            aq0 += x0[0].x*uq0.x + x0[0].y*uq0.y + x0[0].z*uq0.z + x0[0].w*uq0.w
                 + x1[0].x*uq1.x + x1[0].y*uq1.y + x1[0].z*uq1.z + x1[0].w*uq1.w;
            aq1 += x0[1].x*uq0.x + x0[1].y*uq0.y + x0[1].z*uq0.z + x0[1].w*uq0.w
                 + x1[1].x*uq1.x + x1[1].y*uq1.y + x1[1].z*uq1.z + x1[1].w*uq1.w;
            ak0 += x0[0].x*uk0.x + x0[0].y*uk0.y + x0[0].z*uk0.z + x0[0].w*uk0.w
                 + x1[0].x*uk1.x + x1[0].y*uk1.y + x1[0].z*uk1.z + x1[0].w*uk1.w;
            ak1 += x0[1].x*uk0.x + x0[1].y*uk0.y + x0[1].z*uk0.z + x0[1].w*uk0.w
                 + x1[1].x*uk1.x + x1[1].y*uk1.y + x1[1].z*uk1.z + x1[1].w*uk1.w;
        }
        #pragma unroll
        for (int ct = 0; ct < 4; ++ct) {
            int n = wave*64 + ct*16 + l16;
            bf16x8 bh = *(const bf16x8*)(Wh + (size_t)n*DD + kq);
            bf16x8 bl = *(const bf16x8*)(Wl + (size_t)n*DD + kq);
            #pragma unroll
            for (int rt = 0; rt < 2; ++rt) {
                acc[rt][ct] = __builtin_amdgcn_mfma_f32_16x16x32_bf16(ah[rt], bh, acc[rt][ct], 0, 0, 0);
                acc[rt][ct] = __builtin_amdgcn_mfma_f32_16x16x32_bf16(ah[rt], bl, acc[rt][ct], 0, 0, 0);
                acc[rt][ct] = __builtin_amdgcn_mfma_f32_16x16x32_bf16(al[rt], bh, acc[rt][ct], 0, 0, 0);
            }
        }
    }
    #pragma unroll
    for (int rt = 0; rt < 2; ++rt)
        #pragma unroll
        for (int ct = 0; ct < 4; ++ct)
            #pragma unroll
            for (int i = 0; i < 4; ++i)
                V[(size_t)(rowBase + rt*16 + quad*4 + i)*DD + wave*64 + ct*16 + l16]
                    = acc[rt][ct][i];
    if (wave == 0) {
        aq0 += __shfl_xor(aq0, 16); aq0 += __shfl_xor(aq0, 32);
        aq1 += __shfl_xor(aq1, 16); aq1 += __shfl_xor(aq1, 32);
        ak0 += __shfl_xor(ak0, 16); ak0 += __shfl_xor(ak0, 32);
        ak1 += __shfl_xor(ak1, 16); ak1 += __shfl_xor(ak1, 32);
        if (lane < 16) {
            float bias = bmlp[0];
            a[rowBase + lane]      = aq0 + bias;
            a[rowBase + 16 + lane] = aq1 + bias;
            c[rowBase + lane]      = ak0;
            c[rowBase + 16 + lane] = ak1;
        }
    }
}

// ---------------- K3: counting sort by value-bin + SE prefix ----------------
__global__ void __launch_bounds__(1024) k_sortish(const float* __restrict__ c,
        int* __restrict__ binstart_g, int* __restrict__ perm,
        float* __restrict__ c_sorted, float* __restrict__ e_sorted,
        float* __restrict__ SE, float* __restrict__ hdr) {
    __shared__ float cl[LL];
    __shared__ int   hist[NB];
    __shared__ float esl[LL];
    __shared__ float scrf[64];
    int b = blockIdx.x, tid = threadIdx.x;
    int wave = tid >> 6, lane = tid & 63;
    int* scri = (int*)scrf;

    float4 cv = ((const float4*)(c + (size_t)b*LL))[tid];
    ((float4*)cl)[tid] = cv;
    float cw[4] = {cv.x, cv.y, cv.z, cv.w};
    float mn = fminf(fminf(cw[0],cw[1]), fminf(cw[2],cw[3]));
    float mx = fmaxf(fmaxf(cw[0],cw[1]), fmaxf(cw[2],cw[3]));
    #pragma unroll
    for (int off = 32; off > 0; off >>= 1) {
        mn = fminf(mn, __shfl_down(mn, off));
        mx = fmaxf(mx, __shfl_down(mx, off));
    }
    if (lane == 0) { scrf[wave] = mn; scrf[32 + wave] = mx; }
    __syncthreads();
    if (wave == 0) {
        float m = (lane < 16) ? scrf[lane]      :  3.4e38f;
        float M = (lane < 16) ? scrf[32 + lane] : -3.4e38f;
        #pragma unroll
        for (int off = 32; off > 0; off >>= 1) {
            m = fminf(m, __shfl_down(m, off));
            M = fmaxf(M, __shfl_down(M, off));
        }
        if (lane == 0) { scrf[0] = m; scrf[1] = M; }
    }
    __syncthreads();
    float cmin = scrf[0], cmax = scrf[1];
    float scale = (float)NB / fmaxf(cmax - cmin, 1e-20f);
    __syncthreads();

    ((int4*)hist)[tid] = make_int4(0,0,0,0);
    ((int4*)hist)[tid + 1024] = make_int4(0,0,0,0);
    __syncthreads();

    int bins[4];
    #pragma unroll
    for (int u = 0; u < 4; ++u) {
        int bi = (int)((cw[u] - cmin) * scale);
        bi = bi < 0 ? 0 : (bi > NB-1 ? NB-1 : bi);
        bins[u] = bi;
        atomicAdd(&hist[bi], 1);
    }
    __syncthreads();

    int loc[8]; int base = 0;
    #pragma unroll
    for (int j = 0; j < 8; ++j) { loc[j] = base; base += hist[tid*8 + j]; }
    int incl = base;
    #pragma unroll
    for (int off = 1; off < 64; off <<= 1) {
        int t = __shfl_up(incl, off);
        if (lane >= off) incl += t;
    }
    if (lane == 63) scri[wave] = incl;
    __syncthreads();
    if (wave == 0) {
        int v = (lane < 16) ? scri[lane] : 0;
        int s = v;
        #pragma unroll
        for (int off = 1; off < 16; off <<= 1) {
            int t = __shfl_up(s, off);
            if (lane >= off) s += t;
        }
        if (lane < 16) scri[lane] = s - v;
    }
    __syncthreads();
    int thread_excl = (incl - base) + scri[wave];
    __syncthreads();
    #pragma unroll
    for (int j = 0; j < 8; ++j) {
        int bs = thread_excl + loc[j];
        binstart_g[(size_t)b*(NB+2) + tid*8 + j] = bs;
        hist[tid*8 + j] = bs;
    }
    if (tid == 0) {
        binstart_g[(size_t)b*(NB+2) + NB]     = LL;
        binstart_g[(size_t)b*(NB+2) + NB + 1] = LL;
        hdr[b*2 + 0] = cmin;
        hdr[b*2 + 1] = scale;
    }
    __syncthreads();

    #pragma unroll
    for (int u = 0; u < 4; ++u) {
        int i = tid*4 + u;
        int r = atomicAdd(&hist[bins[u]], 1);
        float e = expf(cmin - cw[u]);
        perm[(size_t)b*LL + r] = i;
        c_sorted[(size_t)b*LL + r] = cw[u];
        e_sorted[(size_t)b*LL + r] = e;
        esl[r] = e;
    }
    __syncthreads();

    float le[4]; float s0 = 0.f;
    #pragma unroll
    for (int u = 0; u < 4; ++u) { le[u] = s0; s0 += esl[tid*4 + u]; }
    float fincl = s0;
    #pragma unroll
    for (int off = 1; off < 64; off <<= 1) {
        float t = __shfl_up(fincl, off);
        if (lane >= off) fincl += t;
    }
    if (lane == 63) scrf[wave] = fincl;
    __syncthreads();
    if (wave == 0) {
        float v = (lane < 16) ? scrf[lane] : 0.f;
        float s = v;
        #pragma unroll
        for (int off = 1; off < 16; off <<= 1) {
            float t = __shfl_up(s, off);
            if (lane >= off) s += t;
        }
        if (lane < 16) scrf[lane] = s - v;
    }
    __syncthreads();
    float texcl = (fincl - s0) + scrf[wave];
    #pragma unroll
    for (int u = 0; u < 4; ++u)
        SE[(size_t)b*(LL+1) + tid*4 + u] = texcl + le[u];
    if (tid == 1023) SE[(size_t)b*(LL+1) + LL] = texcl + s0;
}

// ---------------- K4: chunked exclusive prefix over V in rank order ----------------
__global__ void k_scan(const float* __restrict__ V, const int* __restrict__ perm,
        const float* __restrict__ e_sorted,
        float* __restrict__ Pl, float* __restrict__ Pel,
        float* __restrict__ Tp, float* __restrict__ Te) {
    int b = blockIdx.y, q = blockIdx.x;
    int d = threadIdx.x;
    __shared__ int pj[CHUNK];
    __shared__ float pe[CHUNK];
    if (d < CHUNK) {
        pj[d] = perm[(size_t)b*LL + q*CHUNK + d];
        pe[d] = e_sorted[(size_t)b*LL + q*CHUNK + d];
    }
    __syncthreads();
    float vr[CHUNK];
    #pragma unroll
    for (int r = 0; r < CHUNK; ++r)
        vr[r] = V[((size_t)b*LL + pj[r]) * DD + d];
    float acc = 0.f, acce = 0.f;
    size_t kb = (size_t)b*LL + (size_t)q*CHUNK;
    #pragma unroll
    for (int r = 0; r < CHUNK; ++r) {
        size_t o = (kb + r) * DD + d;
        Pl[o]  = acc;
        Pel[o] = acce;
        acc += vr[r];
        acce = fmaf(pe[r], vr[r], acce);
    }
    size_t to = ((size_t)b*NC + q) * DD + d;
    Tp[to] = acc;
    Te[to] = acce;
}

// ---------------- K5: chunk bases, parallel over (q, b) ----------------
__global__ void k_base(const float* __restrict__ Tp, const float* __restrict__ Te,
        float* __restrict__ baseP, float* __restrict__ basePe) {
    int q = blockIdx.x, b = blockIdx.y, d = threadIdx.x;
    float acc = 0.f, acce = 0.f;
    #pragma unroll 8
    for (int i = 0; i < q; ++i) {
        size_t ti = ((size_t)b*NC + i) * DD + d;
        acc += Tp[ti]; acce += Te[ti];
    }
    size_t o = ((size_t)b*(NC+1) + q) * DD + d;
    baseP[o] = acc; basePe[o] = acce;
}

// ---------------- K6: per-row output, O(1) bin lookup + exact boundary fix ----------------
__global__ void k_out(const float* __restrict__ a, const float* __restrict__ hdr,
                      const int* __restrict__ binstart,
                      const float* __restrict__ c_sorted, const float* __restrict__ e_sorted,
                      const int* __restrict__ perm, const float* __restrict__ V,
                      const float* __restrict__ SE,
                      const float* __restrict__ Pl, const float* __restrict__ Pel,
                      const float* __restrict__ baseP, const float* __restrict__ basePe,
                      float* __restrict__ out) {
    int row = blockIdx.x * 4 + (threadIdx.x >> 6);
    int lane = threadIdx.x & 63;
    int b = row >> 12;
    float ai = a[row];
    float cmin = hdr[b*2 + 0], scale = hdr[b*2 + 1];
    float t = (ai - cmin) * scale;
    int ib = t < 0.f ? 0 : (t >= (float)NB ? NB : (int)t);
    int k    = binstart[(size_t)b*(NB+2) + ib];
    int kend = binstart[(size_t)b*(NB+2) + ib + 1];
    float alpha = expf(cmin - ai);
    float Z = fmaf(alpha, (float)(LL - k), SE[(size_t)b*(LL+1) + k]);
    size_t db = (size_t)lane * 4;
    size_t totoff = ((size_t)b * (NC+1) + NC) * DD + db;
    float4 ptot  = *(const float4*)(baseP  + totoff);
    float4 pk, pek;
    if (k < LL) {
        int q = k >> 5;
        size_t po = ((size_t)b * LL + k) * DD + db;
        size_t bo = ((size_t)b * (NC+1) + q) * DD + db;
        float4 pl = *(const float4*)(Pl    + po);
        float4 bp = *(const float4*)(baseP + bo);
        float4 pe = *(const float4*)(Pel    + po);
        float4 be = *(const float4*)(basePe + bo);
        pk.x = pl.x + bp.x; pk.y = pl.y + bp.y; pk.z = pl.z + bp.z; pk.w = pl.w + bp.w;
        pek.x = pe.x + be.x; pek.y = pe.y + be.y; pek.z = pe.z + be.z; pek.w = pe.w + be.w;
    } else {
        pk = ptot;
        pek = *(const float4*)(basePe + totoff);
    }
    float4 num;
    num.x = fmaf(alpha, ptot.x - pk.x, pek.x);
    num.y = fmaf(alpha, ptot.y - pk.y, pek.y);
    num.z = fmaf(alpha, ptot.z - pk.z, pek.z);
    num.w = fmaf(alpha, ptot.w - pk.w, pek.w);
    for (int r = k; r < kend; ++r) {
        float cr = c_sorted[(size_t)b*LL + r];
        if (cr < ai) {
            float w = e_sorted[(size_t)b*LL + r] - alpha;
            int j = perm[(size_t)b*LL + r];
            float4 v = *(const float4*)(V + ((size_t)b*LL + j) * DD + db);
            num.x = fmaf(w, v.x, num.x);
            num.y = fmaf(w, v.y, num.y);
            num.z = fmaf(w, v.z, num.z);
            num.w = fmaf(w, v.w, num.w);
            Z += w;
        }
    }
    float invZ = 1.f / Z;
    float4 o;
    o.x = num.x * invZ; o.y = num.y * invZ; o.z = num.z * invZ; o.w = num.w * invZ;
    *(float4*)(out + (size_t)row * DD + db) = o;
}

extern "C" void kernel_launch(void* const* d_in, const int* in_sizes, int n_in,
                              void* d_out, int out_size, void* d_ws, size_t ws_size,
                              hipStream_t stream) {
    const float* x  = (const float*)d_in[0];
    const float* Wq = (const float*)d_in[1];
    const float* Wk = (const float*)d_in[2];
    const float* Wv = (const float*)d_in[3];
    const float* wm = (const float*)d_in[4];
    const float* bm = (const float*)d_in[5];
    float* out = (float*)d_out;
    float* ws = (float*)d_ws;

    size_t off = 0;
    auto alloc = [&](size_t n) {      // n in floats
        float* p = ws + off;
        off += (n + 255) & ~(size_t)255;
        return p;
    };
    float* u        = alloc(2*DD);
    float* a        = alloc(NROWS);
    float* c        = alloc(NROWS);
    float* c_sorted = alloc(NROWS);
    float* e_sorted = alloc(NROWS);
    float* SE       = alloc((size_t)BB*(LL+1));
    int*   perm     = (int*)alloc(NROWS);
    int*   binstart = (int*)alloc((size_t)BB*(NB+2));
    float* hdr      = alloc(2*BB);
    float* V        = alloc((size_t)NROWS*DD);
    float* Pl       = alloc((size_t)NROWS*DD);
    float* Pel      = alloc((size_t)NROWS*DD);
    float* Tp       = alloc((size_t)BB*NC*DD);
    float* Te       = alloc((size_t)BB*NC*DD);
    float* baseP    = alloc((size_t)BB*(NC+1)*DD);
    float* basePe   = alloc((size_t)BB*(NC+1)*DD);
    __bf16* Wh      = (__bf16*)alloc((size_t)DD*DD/2);
    __bf16* Wl      = (__bf16*)alloc((size_t)DD*DD/2);

    hipLaunchKernelGGL(k_prep, dim3(16), dim3(256), 0, stream, Wq, Wk, Wv, wm, u, Wh, Wl);
    hipLaunchKernelGGL(k_gemm, dim3(NROWS/32), dim3(256), 0, stream,
                       x, Wh, Wl, u, bm, V, a, c);
    hipLaunchKernelGGL(k_sortish, dim3(BB), dim3(1024), 0, stream,
                       c, binstart, perm, c_sorted, e_sorted, SE, hdr);
    hipLaunchKernelGGL(k_scan, dim3(NC, BB), dim3(DD), 0, stream, V, perm, e_sorted, Pl, Pel, Tp, Te);
    hipLaunchKernelGGL(k_base, dim3(NC+1, BB), dim3(DD), 0, stream, Tp, Te, baseP, basePe);
    hipLaunchKernelGGL(k_out, dim3(NROWS/4), dim3(256), 0, stream,
                       a, hdr, binstart, c_sorted, e_sorted, perm, V,
                       SE, Pl, Pel, baseP, basePe, out);
}